// Round 15
// baseline (352.514 us; speedup 1.0000x reference)
//
#include <hip/hip_runtime.h>

#define NN  8000
#define EE  200000
#define BB  4
#define VV  20
#define NVV 8000
#define NRR 200
#define HH  128
#define OO  64
#define LL  3
#define NPB 8    // nodes per block (proj)
#define NPG 4    // nodes per block (gather)
#define NG  2000 // nodes per graph

// ---------------- node projection, 8 nodes/block + per-layer alpha dots ----------------
__global__ __launch_bounds__(128) void k_proj_nodes(
    const int* __restrict__ node_ids, const float* __restrict__ emb,
    const float* __restrict__ lin_w, const float* __restrict__ lin_b,
    const float* __restrict__ alpha_w, float* __restrict__ x,
    float* __restrict__ snode)
{
  int blk = blockIdx.x, t = threadIdx.x;
  __shared__ float er[NPB][HH];
  __shared__ float part[LL][NPB][2];
  int base = blk * NPB;
  #pragma unroll
  for (int n = 0; n < NPB; ++n)
    er[n][t] = emb[node_ids[base + n] * HH + t];
  __syncthreads();
  float bt = lin_b[t];
  float acc[NPB];
  #pragma unroll
  for (int n = 0; n < NPB; ++n) acc[n] = bt;
  for (int d4 = 0; d4 < HH / 4; ++d4) {
    float e4[NPB][4];
    #pragma unroll
    for (int n = 0; n < NPB; ++n) {
      float4 v = *(const float4*)&er[n][d4 * 4];
      e4[n][0] = v.x; e4[n][1] = v.y; e4[n][2] = v.z; e4[n][3] = v.w;
    }
    #pragma unroll
    for (int j = 0; j < 4; ++j) {
      float lwv = lin_w[(d4 * 4 + j) * HH + t];
      #pragma unroll
      for (int n = 0; n < NPB; ++n) acc[n] += e4[n][j] * lwv;
    }
  }
  #pragma unroll
  for (int n = 0; n < NPB; ++n) x[(base + n) * HH + t] = acc[n];
  #pragma unroll
  for (int l = 0; l < LL; ++l) {
    float aw = alpha_w[l * HH + t];
    #pragma unroll
    for (int n = 0; n < NPB; ++n) {
      float v = acc[n] * aw;
      for (int off = 32; off > 0; off >>= 1) v += __shfl_down(v, off, 64);
      if ((t & 63) == 0) part[l][n][t >> 6] = v;
    }
  }
  __syncthreads();
  if (t < LL * NPB) {
    int l = t / NPB, n = t % NPB;
    snode[l * NN + base + n] = part[l][n][0] + part[l][n][1];
  }
}

// ---------------- fused: relation projection (blocks 0..199) + beta (200..211) + zeroing ----------------
__global__ __launch_bounds__(128) void k_prb(
    const float* __restrict__ rel_emb, const float* __restrict__ lin_w,
    const float* __restrict__ lin_b, const float* __restrict__ wr_w,
    const float* __restrict__ wr_b, const float* __restrict__ visit_node,
    const float* __restrict__ beta_w, const float* __restrict__ beta_b,
    float* __restrict__ wrelp, float* __restrict__ beta0,
    int* __restrict__ iz, float* __restrict__ fz)
{
  int blk = blockIdx.x, t = threadIdx.x;
  int idx = blk * 128 + t;
  if (idx < 2 * NN) iz[idx] = 0;                 // deg + cursor
  if (idx < BB * HH * 2 + BB) fz[idx] = 0.f;     // xg_raw + xn_raw + denom
  if (blk < NRR) {
    __shared__ float row[HH];
    __shared__ float part[LL][2];
    row[t] = rel_emb[blk * HH + t];
    __syncthreads();
    float acc = lin_b[t];
    #pragma unroll 4
    for (int d = 0; d < HH; ++d) acc += row[d] * lin_w[d * HH + t];
    #pragma unroll
    for (int l = 0; l < LL; ++l) {
      float v = acc * wr_w[l * HH + t];
      for (int off = 32; off > 0; off >>= 1) v += __shfl_down(v, off, 64);
      if ((t & 63) == 0) part[l][t >> 6] = v;
    }
    __syncthreads();
    #pragma unroll
    for (int l = 0; l < LL; ++l) {
      float rd = part[l][0] + part[l][1] + wr_b[l];
      wrelp[(l * NRR + blk) * HH + t] = rd * acc;
    }
  } else {
    int j = blk - NRR;          // 0..11
    int l = j >> 2, b = j & 3;
    float acc = 0.f;
    for (int n = t; n < NVV; n += 128)
      acc += visit_node[(b * VV + 0) * NVV + n] * beta_w[l * NVV + n];
    for (int off = 32; off > 0; off >>= 1) acc += __shfl_down(acc, off, 64);
    __shared__ float bred[2];
    if ((t & 63) == 0) bred[t >> 6] = acc;
    __syncthreads();
    if (t == 0)
      beta0[l * BB + b] = tanhf(bred[0] + bred[1] + beta_b[l]) * expf(0.03f * 20.0f);
  }
}

// ---------------- fused: per-node attention (softmax col @ node) + degree histogram ----------------
__global__ __launch_bounds__(256) void k_anode_hist(
    const int* __restrict__ node_ids, const int* __restrict__ batch,
    const int* __restrict__ edge_index, const float* __restrict__ visit_node,
    const float* __restrict__ snode, const float* __restrict__ alpha_b,
    const float* __restrict__ beta0, float* __restrict__ anode,
    int* __restrict__ deg)
{
  int idx = blockIdx.x * 256 + threadIdx.x;
  if (idx < EE) atomicAdd(&deg[edge_index[EE + idx]], 1);
  if (idx >= NN) return;
  int b = batch[idx], nid = node_ids[idx];
  float vn[VV];
  #pragma unroll
  for (int v = 0; v < VV; ++v) vn[v] = visit_node[(b * VV + v) * NVV + nid];
  #pragma unroll
  for (int l = 0; l < LL; ++l) {
    float s = (nid < NG) ? snode[l * NN + b * NG + nid] : 0.0f;
    float ab = alpha_b[l];
    float m = -1e30f;
    #pragma unroll
    for (int v = 0; v < VV; ++v) m = fmaxf(m, vn[v] * s + ab);
    float sum = 0.f;
    #pragma unroll
    for (int v = 0; v < VV; ++v) sum += expf(vn[v] * s + ab - m);
    anode[l * NN + idx] = (expf(vn[0] * s + ab - m) / sum) * beta0[l * BB + b];
  }
}

// ---------------- scan (row_ptr) ----------------
__global__ __launch_bounds__(1024) void k_scan(const int* __restrict__ deg,
                                               int* __restrict__ row_ptr)
{
  int t = threadIdx.x;
  __shared__ int ps[1024];
  int local[8];
  int base = t * 8;
  int s = 0;
  #pragma unroll
  for (int j = 0; j < 8; ++j) {
    int idx = base + j;
    int v = (idx < NN) ? deg[idx] : 0;
    local[j] = s; s += v;
  }
  ps[t] = s;
  __syncthreads();
  for (int off = 1; off < 1024; off <<= 1) {
    int v = (t >= off) ? ps[t - off] : 0;
    __syncthreads();
    ps[t] += v;
    __syncthreads();
  }
  int excl = (t == 0) ? 0 : ps[t - 1];
  #pragma unroll
  for (int j = 0; j < 8; ++j) {
    int idx = base + j;
    if (idx < NN) row_ptr[idx] = excl + local[j];
  }
  if (t == 1023) row_ptr[NN] = ps[1023];
}

// ---------------- scatter: CSR (src, rid) only ----------------
__global__ void k_scatter(const int* __restrict__ edge_index, const int* __restrict__ rel_ids,
                          const int* __restrict__ row_ptr, int* __restrict__ cursor,
                          int2* __restrict__ csr_sr)
{
  int e = blockIdx.x * 256 + threadIdx.x;
  if (e >= EE) return;
  int dst = edge_index[EE + e];
  int p = row_ptr[dst] + atomicAdd(&cursor[dst], 1);
  csr_sr[p] = make_int2(edge_index[e], rel_ids[e]);
}

// ---------------- fused gather + conv ----------------
// 4 nodes/block; 2 sub-warps (32 lanes each) split each node's edge range
// to halve the serial latency chain; conv uses all 64 lanes/node (float2).
__global__ __launch_bounds__(256) void k_gather_conv(
    const int* __restrict__ row_ptr, const int2* __restrict__ csr_sr,
    const float* __restrict__ anode, const float* __restrict__ xin,
    const float* __restrict__ wrelp, const float* __restrict__ conv_w,
    const float* __restrict__ conv_b, float* __restrict__ xout, int l)
{
  int t = threadIdx.x;
  int node_sub = t >> 6;        // 0..3
  int half = (t >> 5) & 1;      // which edge-half
  int lane = t & 31;            // lane within gather group
  int lane64 = t & 63;          // lane within node (conv/combine)
  int i = blockIdx.x * NPG + node_sub;
  __shared__ float part[2][NPG][HH];   // 4 KB
  const float4* __restrict__ xin4 = (const float4*)xin;
  const float2* __restrict__ xin2 = (const float2*)xin;
  const float4* __restrict__ wr4 = (const float4*)wrelp + (size_t)l * NRR * 32;
  const float* __restrict__ an = anode + (size_t)l * NN;

  int k0 = row_ptr[i], k1 = row_ptr[i + 1];
  int cnt = k1 - k0;
  int halfcnt = (cnt + 1) >> 1;
  int ks = k0 + half * halfcnt;
  int ke = half ? k1 : (k0 + halfcnt);

  float4 accA = make_float4(0.f, 0.f, 0.f, 0.f);
  float4 accB = make_float4(0.f, 0.f, 0.f, 0.f);
  int k = ks;
  for (; k + 3 < ke; k += 4) {
    int2 s0 = csr_sr[k],     s1 = csr_sr[k + 1];
    int2 s2 = csr_sr[k + 2], s3 = csr_sr[k + 3];
    float a0 = an[s0.x], a1 = an[s1.x], a2 = an[s2.x], a3 = an[s3.x];
    float4 x0 = xin4[s0.x * 32 + lane], w0 = wr4[s0.y * 32 + lane];
    float4 x1 = xin4[s1.x * 32 + lane], w1 = wr4[s1.y * 32 + lane];
    float4 x2 = xin4[s2.x * 32 + lane], w2 = wr4[s2.y * 32 + lane];
    float4 x3 = xin4[s3.x * 32 + lane], w3 = wr4[s3.y * 32 + lane];
    accA.x += fmaxf(x0.x * a0 + w0.x, 0.f) + fmaxf(x1.x * a1 + w1.x, 0.f);
    accA.y += fmaxf(x0.y * a0 + w0.y, 0.f) + fmaxf(x1.y * a1 + w1.y, 0.f);
    accA.z += fmaxf(x0.z * a0 + w0.z, 0.f) + fmaxf(x1.z * a1 + w1.z, 0.f);
    accA.w += fmaxf(x0.w * a0 + w0.w, 0.f) + fmaxf(x1.w * a1 + w1.w, 0.f);
    accB.x += fmaxf(x2.x * a2 + w2.x, 0.f) + fmaxf(x3.x * a3 + w3.x, 0.f);
    accB.y += fmaxf(x2.y * a2 + w2.y, 0.f) + fmaxf(x3.y * a3 + w3.y, 0.f);
    accB.z += fmaxf(x2.z * a2 + w2.z, 0.f) + fmaxf(x3.z * a3 + w3.z, 0.f);
    accB.w += fmaxf(x2.w * a2 + w2.w, 0.f) + fmaxf(x3.w * a3 + w3.w, 0.f);
  }
  for (; k < ke; ++k) {
    int2 s0 = csr_sr[k];
    float a0 = an[s0.x];
    float4 x0 = xin4[s0.x * 32 + lane], w0 = wr4[s0.y * 32 + lane];
    accA.x += fmaxf(x0.x * a0 + w0.x, 0.f);
    accA.y += fmaxf(x0.y * a0 + w0.y, 0.f);
    accA.z += fmaxf(x0.z * a0 + w0.z, 0.f);
    accA.w += fmaxf(x0.w * a0 + w0.w, 0.f);
  }
  accA.x += accB.x; accA.y += accB.y; accA.z += accB.z; accA.w += accB.w;
  *(float4*)&part[half][node_sub][lane * 4] = accA;
  __syncthreads();

  // combine halves + residual x, store agg row back into part[0]
  {
    float2 p0 = *(const float2*)&part[0][node_sub][lane64 * 2];
    float2 p1 = *(const float2*)&part[1][node_sub][lane64 * 2];
    float2 xi = xin2[(size_t)i * 64 + lane64];
    float2 ag = make_float2(xi.x + p0.x + p1.x, xi.y + p0.y + p1.y);
    __syncthreads();
    *(float2*)&part[0][node_sub][lane64 * 2] = ag;
  }
  __syncthreads();

  // conv: 64 lanes per node, 2 output features each
  const float2* __restrict__ cwb = (const float2*)conv_w + (size_t)l * HH * 64;
  float2 o = ((const float2*)conv_b)[l * 64 + lane64];
  for (int d4 = 0; d4 < HH / 4; ++d4) {
    float4 agv = *(const float4*)&part[0][node_sub][d4 * 4];
    float2 c0 = cwb[(d4 * 4 + 0) * 64 + lane64];
    float2 c1 = cwb[(d4 * 4 + 1) * 64 + lane64];
    float2 c2 = cwb[(d4 * 4 + 2) * 64 + lane64];
    float2 c3 = cwb[(d4 * 4 + 3) * 64 + lane64];
    o.x += agv.x * c0.x + agv.y * c1.x + agv.z * c2.x + agv.w * c3.x;
    o.y += agv.x * c0.y + agv.y * c1.y + agv.z * c2.y + agv.w * c3.y;
  }
  o.x = fmaxf(o.x, 0.f);
  o.y = fmaxf(o.y, 0.f);
  ((float2*)xout)[(size_t)i * 64 + lane64] = o;
}

// ---------------- fused pooling: x_graph (blocks 0..63) + x_node (64..191) ----------------
__global__ __launch_bounds__(128) void k_pool(
    const float* __restrict__ x, const float* __restrict__ ehr,
    const float* __restrict__ emb, float* __restrict__ xg_raw,
    float* __restrict__ xn_raw, float* __restrict__ denom)
{
  int t = threadIdx.x;
  if (blockIdx.x < 64) {
    int b = blockIdx.x >> 4, c = blockIdx.x & 15;
    const int per = NG / 16;
    int base = b * NG + c * per;
    float acc = 0.f;
    for (int i = 0; i < per; ++i) acc += x[(base + i) * HH + t];
    atomicAdd(&xg_raw[b * HH + t], acc);
  } else {
    int ib = blockIdx.x - 64;
    int b = ib >> 5, c = ib & 31;
    const int per = NVV / 32;
    int base = c * per;
    float acc = 0.f;
    for (int n = base; n < base + per; ++n)
      acc += ehr[b * NVV + n] * emb[n * HH + t];
    atomicAdd(&xn_raw[b * HH + t], acc);
    __shared__ float red[128];
    float dsum = 0.f;
    for (int n = base + t; n < base + per; n += 128) dsum += ehr[b * NVV + n];
    red[t] = dsum;
    __syncthreads();
    for (int s = 64; s > 0; s >>= 1) {
      if (t < s) red[t] += red[t + s];
      __syncthreads();
    }
    if (t == 0) atomicAdd(&denom[b], red[0]);
  }
}

// ---------------- final: project x_node, concat, MLP ----------------
__global__ __launch_bounds__(128) void k_final(
    const float* __restrict__ xg_raw, const float* __restrict__ xn_raw,
    const float* __restrict__ denom, const float* __restrict__ lin_w,
    const float* __restrict__ lin_b, const float* __restrict__ mlp_w,
    const float* __restrict__ mlp_b, float* __restrict__ out)
{
  int b = blockIdx.x, t = threadIdx.x;
  __shared__ float xg[HH], xn[HH], xnp[HH];
  xg[t] = xg_raw[b * HH + t] * (1.0f / NG);
  xn[t] = xn_raw[b * HH + t] / denom[b];
  __syncthreads();
  float a3 = lin_b[t];
  #pragma unroll 4
  for (int d = 0; d < HH; ++d) a3 += xn[d] * lin_w[d * HH + t];
  xnp[t] = a3;
  __syncthreads();
  if (t < OO) {
    float a4 = mlp_b[t];
    #pragma unroll 4
    for (int h = 0; h < HH; ++h)
      a4 += xg[h] * mlp_w[h * OO + t] + xnp[h] * mlp_w[(HH + h) * OO + t];
    out[b * OO + t] = a4;
  }
}

extern "C" void kernel_launch(void* const* d_in, const int* in_sizes, int n_in,
                              void* d_out, int out_size, void* d_ws, size_t ws_size,
                              hipStream_t stream) {
  const int*   node_ids   = (const int*)d_in[0];
  const int*   rel_ids    = (const int*)d_in[1];
  const int*   edge_index = (const int*)d_in[2];
  const int*   batch      = (const int*)d_in[3];
  const float* visit_node = (const float*)d_in[4];
  const float* ehr        = (const float*)d_in[5];
  const float* node_emb   = (const float*)d_in[6];
  const float* rel_emb    = (const float*)d_in[7];
  const float* lin_w      = (const float*)d_in[8];
  const float* lin_b      = (const float*)d_in[9];
  const float* alpha_w    = (const float*)d_in[10];
  const float* alpha_b    = (const float*)d_in[11];
  const float* beta_w     = (const float*)d_in[12];
  const float* beta_b     = (const float*)d_in[13];
  const float* conv_w     = (const float*)d_in[14];
  const float* conv_b     = (const float*)d_in[15];
  const float* wr_w       = (const float*)d_in[16];
  const float* wr_b       = (const float*)d_in[17];
  const float* mlp_w      = (const float*)d_in[18];
  const float* mlp_b      = (const float*)d_in[19];
  float* out = (float*)d_out;

  float* ws = (float*)d_ws;
  float* xA     = ws; ws += NN * HH;
  float* xB     = ws; ws += NN * HH;
  float* wrelp  = ws; ws += LL * NRR * HH;
  float* snode  = ws; ws += LL * NN;
  float* beta0  = ws; ws += LL * BB;
  float* anode  = ws; ws += LL * NN;
  float* xg_raw = ws; ws += BB * HH;   // xg_raw/xn_raw/denom contiguous (zeroed together)
  float* xn_raw = ws; ws += BB * HH;
  float* denom  = ws; ws += BB;
  int* iws      = (int*)ws;
  int* deg      = iws; iws += NN;      // deg/cursor contiguous (zeroed together)
  int* cursor   = iws; iws += NN;
  int* row_ptr  = iws; iws += NN + 2;  // +2 pad -> csr_sr stays 8B-aligned
  int2* csr_sr  = (int2*)iws;

  // 1: node projection + snode
  hipLaunchKernelGGL(k_proj_nodes, dim3(NN / NPB), dim3(HH), 0, stream,
                     node_ids, node_emb, lin_w, lin_b, alpha_w, xA, snode);
  // 2: rel projection + beta + zero(deg,cursor,accum)
  hipLaunchKernelGGL(k_prb, dim3(NRR + LL * BB), dim3(HH), 0, stream,
                     rel_emb, lin_w, lin_b, wr_w, wr_b, visit_node, beta_w,
                     beta_b, wrelp, beta0, deg, xg_raw);
  // 3: per-node attention + degree histogram
  hipLaunchKernelGGL(k_anode_hist, dim3((EE + 255) / 256), dim3(256), 0, stream,
                     node_ids, batch, edge_index, visit_node, snode, alpha_b,
                     beta0, anode, deg);
  // 4: scan
  hipLaunchKernelGGL(k_scan, dim3(1), dim3(1024), 0, stream, deg, row_ptr);
  // 5: scatter
  hipLaunchKernelGGL(k_scatter, dim3((EE + 255) / 256), dim3(256), 0, stream,
                     edge_index, rel_ids, row_ptr, cursor, csr_sr);
  // 6-8: layers
  const float* xin = xA;
  float* xout = xB;
  for (int l = 0; l < LL; ++l) {
    hipLaunchKernelGGL(k_gather_conv, dim3(NN / NPG), dim3(256), 0, stream,
                       row_ptr, csr_sr, anode, xin, wrelp, conv_w, conv_b, xout, l);
    const float* tmp = xin; xin = xout; xout = (float*)tmp;
  }
  // final x in xB (A->B, B->A, A->B)
  // 9: pooling (x_graph + x_node partials)
  hipLaunchKernelGGL(k_pool, dim3(64 + 128), dim3(HH), 0, stream,
                     xB, ehr, node_emb, xg_raw, xn_raw, denom);
  // 10: head
  hipLaunchKernelGGL(k_final, dim3(BB), dim3(HH), 0, stream,
                     xg_raw, xn_raw, denom, lin_w, lin_b, mlp_w, mlp_b, out);
}